// Round 5
// baseline (1709.676 us; speedup 1.0000x reference)
//
#include <hip/hip_runtime.h>

// Problem constants (from reference): B=256, T=2048, I=12, H=64
constexpr int Bn = 256;
constexpr int Tn = 2048;
constexpr int In = 12;
constexpr int Hn = 64;
constexpr int Gn = 4 * Hn; // 256 gates

__device__ __forceinline__ float fast_sig(float x) {
    return 1.0f / (1.0f + __expf(-x));
}
__device__ __forceinline__ float fast_tanh(float x) {
    // tanh(x) = sign(x) * (1 - 2e/(1+e)), e = exp(-2|x|)  -- never overflows
    float ax = fabsf(x);
    float e  = __expf(-2.0f * ax);
    float t  = 1.0f - 2.0f * e / (1.0f + e);
    return copysignf(t, x);
}

extern "C" __global__ void __launch_bounds__(256, 1)
lstm_fused_kernel(const float* __restrict__ x,
                  const float* __restrict__ w_ih,
                  const float* __restrict__ w_hh,
                  const float* __restrict__ b_ih,
                  const float* __restrict__ b_hh,
                  const float* __restrict__ fc_w,
                  const float* __restrict__ fc_b,
                  float* __restrict__ out)
{
    extern __shared__ float smem[];
    float* xlds   = smem;               // Tn*In = 24576 floats (96 KiB)
    float* actlds = smem + Tn * In;     // 256 floats
    float* hbuf   = actlds + Gn;        // 64 floats

    const int tid  = threadIdx.x;       // 0..255 == gate index
    const int lane = tid & 63;
    const int wid  = tid >> 6;          // 0:i 1:f 2:g 3:o (gate type)
    const int b    = blockIdx.x;        // batch row

    // ---- stage entire x row into LDS (coalesced float4) ----
    {
        const float4* xsrc = (const float4*)(x + (size_t)b * Tn * In);
        float4* xdst = (float4*)xlds;
        constexpr int NV = Tn * In / 4; // 6144
        for (int idx = tid; idx < NV; idx += 256) xdst[idx] = xsrc[idx];
    }

    // ---- per-thread weights in registers ----
    float wih[In];
    {
        const float4* wr = (const float4*)(w_ih + tid * In); // 48B-aligned
        float4 v0 = wr[0], v1 = wr[1], v2 = wr[2];
        wih[0]=v0.x; wih[1]=v0.y; wih[2]=v0.z; wih[3]=v0.w;
        wih[4]=v1.x; wih[5]=v1.y; wih[6]=v1.z; wih[7]=v1.w;
        wih[8]=v2.x; wih[9]=v2.y; wih[10]=v2.z; wih[11]=v2.w;
    }
    float whh[Hn];
    {
        const float4* wr = (const float4*)(w_hh + tid * Hn);
        #pragma unroll
        for (int j = 0; j < Hn / 4; ++j) {
            float4 v = wr[j];
            whh[4*j+0]=v.x; whh[4*j+1]=v.y; whh[4*j+2]=v.z; whh[4*j+3]=v.w;
        }
    }
    const float bias = b_ih[tid] + b_hh[tid];
    const float fcw  = fc_w[lane];
    const float fcb  = fc_b[0];

    float c = 0.0f;                      // lane `lane` holds c[lane], redundant per wave
    if (tid < Hn) hbuf[tid] = 0.0f;
    __syncthreads();

    float* outb = out + (size_t)b * Tn;

    for (int t = 0; t < Tn; ++t) {
        // ---- phase A: this thread's gate pre-activation ----
        float a0 = bias, a1 = 0.f, a2 = 0.f, a3 = 0.f;
        {
            const float4* xt4 = (const float4*)(xlds + t * In);
            float4 x0 = xt4[0], x1 = xt4[1], x2 = xt4[2];
            a0 = fmaf(x0.x, wih[0],  a0);  a1 = fmaf(x0.y, wih[1],  a1);
            a2 = fmaf(x0.z, wih[2],  a2);  a3 = fmaf(x0.w, wih[3],  a3);
            a0 = fmaf(x1.x, wih[4],  a0);  a1 = fmaf(x1.y, wih[5],  a1);
            a2 = fmaf(x1.z, wih[6],  a2);  a3 = fmaf(x1.w, wih[7],  a3);
            a0 = fmaf(x2.x, wih[8],  a0);  a1 = fmaf(x2.y, wih[9],  a1);
            a2 = fmaf(x2.z, wih[10], a2);  a3 = fmaf(x2.w, wih[11], a3);
        }
        {
            const float4* h4 = (const float4*)hbuf;
            #pragma unroll
            for (int j = 0; j < Hn / 4; ++j) {
                float4 hv = h4[j];
                a0 = fmaf(hv.x, whh[4*j+0], a0);
                a1 = fmaf(hv.y, whh[4*j+1], a1);
                a2 = fmaf(hv.z, whh[4*j+2], a2);
                a3 = fmaf(hv.w, whh[4*j+3], a3);
            }
        }
        float gate = (a0 + a1) + (a2 + a3);
        float act  = (wid == 2) ? fast_tanh(gate) : fast_sig(gate);
        actlds[tid] = act;
        __syncthreads();

        // ---- phase B: every wave redundantly updates c[lane], h[lane] ----
        float iv = actlds[lane];
        float fv = actlds[64 + lane];
        float gv = actlds[128 + lane];
        float ov = actlds[192 + lane];
        c = fmaf(fv, c, iv * gv);
        float h = ov * fast_tanh(c);
        if (wid == 0) hbuf[lane] = h;

        // ---- fc projection: rotating wave does the 64-lane reduce ----
        if (wid == (t & 3)) {
            float p = h * fcw;
            #pragma unroll
            for (int off = 32; off; off >>= 1) p += __shfl_xor(p, off, 64);
            if (lane == 0) outb[t] = p + fcb;
        }
        __syncthreads();
    }
}

extern "C" void kernel_launch(void* const* d_in, const int* in_sizes, int n_in,
                              void* d_out, int out_size, void* d_ws, size_t ws_size,
                              hipStream_t stream) {
    const float* x    = (const float*)d_in[0];
    const float* w_ih = (const float*)d_in[1];
    const float* w_hh = (const float*)d_in[2];
    const float* b_ih = (const float*)d_in[3];
    const float* b_hh = (const float*)d_in[4];
    const float* fc_w = (const float*)d_in[5];
    const float* fc_b = (const float*)d_in[6];
    float* out = (float*)d_out;

    size_t shmem = (size_t)(Tn * In + Gn + Hn + 16) * sizeof(float); // ~99.6 KiB
    // hipFuncSetAttribute is not a stream op; safe under graph capture.
    hipFuncSetAttribute((const void*)lstm_fused_kernel,
                        hipFuncAttributeMaxDynamicSharedMemorySize, (int)shmem);

    lstm_fused_kernel<<<Bn, 256, shmem, stream>>>(x, w_ih, w_hh, b_ih, b_hh,
                                                  fc_w, fc_b, out);
}

// Round 6
// 1506.105 us; speedup vs baseline: 1.1352x; 1.1352x over previous
//
#include <hip/hip_runtime.h>

// Problem constants (from reference): B=256, T=2048, I=12, H=64
constexpr int Bn = 256;
constexpr int Tn = 2048;
constexpr int In = 12;
constexpr int Hn = 64;
constexpr int Gn = 4 * Hn;   // 256 gates
constexpr int CHUNK = 16;    // fc-flush granularity (register h-history depth)

__device__ __forceinline__ float fast_sig(float x) {
    return 1.0f / (1.0f + __expf(-x));
}
__device__ __forceinline__ float fast_tanh(float x) {
    float ax = fabsf(x);
    float e  = __expf(-2.0f * ax);
    float t  = 1.0f - 2.0f * e / (1.0f + e);
    return copysignf(t, x);
}

extern "C" __global__ void __launch_bounds__(256, 1)
lstm_fused_kernel(const float* __restrict__ x,
                  const float* __restrict__ w_ih,
                  const float* __restrict__ w_hh,
                  const float* __restrict__ b_ih,
                  const float* __restrict__ b_hh,
                  const float* __restrict__ fc_w,
                  const float* __restrict__ fc_b,
                  float* __restrict__ out)
{
    extern __shared__ float smem[];
    float* xlds = smem;                    // Tn*In = 24576 floats (96 KiB)
    float* act0 = smem + Tn * In;          // 256 floats (ping)
    float* act1 = act0 + Gn;               // 256 floats (pong)
    float* hball = act1 + Gn;              // 4*64 floats (per-wave private h)

    const int tid  = threadIdx.x;          // 0..255 == gate row
    const int lane = tid & 63;
    const int wid  = tid >> 6;             // 0:i 1:f 2:g 3:o
    const int b    = blockIdx.x;

    float* hb = hball + wid * Hn;          // this wave's private h copy

    // ---- stage entire x row into LDS (coalesced float4) ----
    {
        const float4* xsrc = (const float4*)(x + (size_t)b * Tn * In);
        float4* xdst = (float4*)xlds;
        constexpr int NV = Tn * In / 4;    // 6144
        for (int idx = tid; idx < NV; idx += 256) xdst[idx] = xsrc[idx];
    }

    // ---- per-thread weights in registers, PINNED via opaque asm anchors ----
    float wih[In];
    {
        const float4* wr = (const float4*)(w_ih + tid * In);
        float4 v0 = wr[0], v1 = wr[1], v2 = wr[2];
        wih[0]=v0.x; wih[1]=v0.y; wih[2]=v0.z;  wih[3]=v0.w;
        wih[4]=v1.x; wih[5]=v1.y; wih[6]=v1.z;  wih[7]=v1.w;
        wih[8]=v2.x; wih[9]=v2.y; wih[10]=v2.z; wih[11]=v2.w;
        #pragma unroll
        for (int j = 0; j < 3; ++j)
            asm volatile("" : "+v"(wih[4*j+0]), "+v"(wih[4*j+1]),
                              "+v"(wih[4*j+2]), "+v"(wih[4*j+3]));
    }
    float whh[Hn];
    {
        const float4* wr = (const float4*)(w_hh + tid * Hn);
        #pragma unroll
        for (int j = 0; j < Hn / 4; ++j) {
            float4 v = wr[j];
            whh[4*j+0]=v.x; whh[4*j+1]=v.y; whh[4*j+2]=v.z; whh[4*j+3]=v.w;
        }
        // Anchors: values become opaque asm outputs -> cannot be sunk or
        // rematerialized by re-loading from global inside the t-loop.
        #pragma unroll
        for (int j = 0; j < Hn / 4; ++j)
            asm volatile("" : "+v"(whh[4*j+0]), "+v"(whh[4*j+1]),
                              "+v"(whh[4*j+2]), "+v"(whh[4*j+3]));
    }
    const float bias = b_ih[tid] + b_hh[tid];
    const float fcw  = fc_w[lane];
    const float fcb  = fc_b[0];

    float c = 0.0f;                        // lane holds c[lane]; replicated per wave
    hb[lane] = 0.0f;                       // own private h copy (h_0 = 0)
    __syncthreads();                       // xlds staged + all init visible

    float* outb = out + (size_t)b * Tn;

    for (int T0 = 0; T0 < Tn; T0 += CHUNK) {
        float p[CHUNK];                    // h history, statically indexed
        #pragma unroll
        for (int s = 0; s < CHUNK; ++s) {
            const int t = T0 + s;
            float* actw = (s & 1) ? act1 : act0;   // compile-time ping-pong

            // ---- phase A: gate pre-activation (x_t from LDS, h from OWN hbuf) ----
            float a0 = bias, a1 = 0.f, a2 = 0.f, a3 = 0.f;
            {
                const float4* xt4 = (const float4*)(xlds + t * In);
                float4 x0 = xt4[0], x1 = xt4[1], x2 = xt4[2];
                a0 = fmaf(x0.x, wih[0],  a0);  a1 = fmaf(x0.y, wih[1],  a1);
                a2 = fmaf(x0.z, wih[2],  a2);  a3 = fmaf(x0.w, wih[3],  a3);
                a0 = fmaf(x1.x, wih[4],  a0);  a1 = fmaf(x1.y, wih[5],  a1);
                a2 = fmaf(x1.z, wih[6],  a2);  a3 = fmaf(x1.w, wih[7],  a3);
                a0 = fmaf(x2.x, wih[8],  a0);  a1 = fmaf(x2.y, wih[9],  a1);
                a2 = fmaf(x2.z, wih[10], a2);  a3 = fmaf(x2.w, wih[11], a3);
            }
            {
                const float4* h4 = (const float4*)hb;  // uniform addr: broadcast reads
                #pragma unroll
                for (int j = 0; j < Hn / 4; ++j) {
                    float4 hv = h4[j];
                    a0 = fmaf(hv.x, whh[4*j+0], a0);
                    a1 = fmaf(hv.y, whh[4*j+1], a1);
                    a2 = fmaf(hv.z, whh[4*j+2], a2);
                    a3 = fmaf(hv.w, whh[4*j+3], a3);
                }
            }
            float gate = (a0 + a1) + (a2 + a3);
            float act  = (wid == 2) ? fast_tanh(gate) : fast_sig(gate);
            actw[tid] = act;
            __syncthreads();               // the ONE barrier per step

            // ---- phase B: every wave redundantly updates c/h for its lane ----
            float iv = actw[lane];
            float fv = actw[64 + lane];
            float gv = actw[128 + lane];
            float ov = actw[192 + lane];
            c = fmaf(fv, c, iv * gv);
            float h = ov * fast_tanh(c);
            p[s] = h;
            hb[lane] = h;                  // own copy only; no cross-wave hazard
            // write->read (next iter) same-wave ordering
            asm volatile("s_waitcnt lgkmcnt(0)" ::: "memory");
        }

        // ---- fc flush: wave w reduces steps [4w, 4w+4) of this chunk ----
        float q0, q1, q2, q3;
        if      (wid == 0) { q0 = p[0];  q1 = p[1];  q2 = p[2];  q3 = p[3];  }
        else if (wid == 1) { q0 = p[4];  q1 = p[5];  q2 = p[6];  q3 = p[7];  }
        else if (wid == 2) { q0 = p[8];  q1 = p[9];  q2 = p[10]; q3 = p[11]; }
        else               { q0 = p[12]; q1 = p[13]; q2 = p[14]; q3 = p[15]; }
        q0 *= fcw; q1 *= fcw; q2 *= fcw; q3 *= fcw;
        #pragma unroll
        for (int off = 32; off; off >>= 1) {
            q0 += __shfl_xor(q0, off, 64);
            q1 += __shfl_xor(q1, off, 64);
            q2 += __shfl_xor(q2, off, 64);
            q3 += __shfl_xor(q3, off, 64);
        }
        if (lane == 0) {
            float4 o4;
            o4.x = q0 + fcb; o4.y = q1 + fcb; o4.z = q2 + fcb; o4.w = q3 + fcb;
            *(float4*)(outb + T0 + 4 * wid) = o4;   // fire-and-forget
        }
    }
}

extern "C" void kernel_launch(void* const* d_in, const int* in_sizes, int n_in,
                              void* d_out, int out_size, void* d_ws, size_t ws_size,
                              hipStream_t stream) {
    const float* x    = (const float*)d_in[0];
    const float* w_ih = (const float*)d_in[1];
    const float* w_hh = (const float*)d_in[2];
    const float* b_ih = (const float*)d_in[3];
    const float* b_hh = (const float*)d_in[4];
    const float* fc_w = (const float*)d_in[5];
    const float* fc_b = (const float*)d_in[6];
    float* out = (float*)d_out;

    // xlds + 2*act + 4*hbuf
    size_t shmem = (size_t)(Tn * In + 2 * Gn + 4 * Hn) * sizeof(float); // ~99 KiB
    hipFuncSetAttribute((const void*)lstm_fused_kernel,
                        hipFuncAttributeMaxDynamicSharedMemorySize, (int)shmem);

    lstm_fused_kernel<<<Bn, 256, shmem, stream>>>(x, w_ih, w_hh, b_ih, b_hh,
                                                  fc_w, fc_b, out);
}

// Round 7
// 1499.100 us; speedup vs baseline: 1.1405x; 1.0047x over previous
//
#include <hip/hip_runtime.h>

// Problem constants (from reference): B=256, T=2048, I=12, H=64
constexpr int Bn = 256;
constexpr int Tn = 2048;
constexpr int In = 12;
constexpr int Hn = 64;
constexpr int Gn = 4 * Hn;   // 256 gates
constexpr int CHUNK = 16;    // fc-flush granularity (register h-history depth)

__device__ __forceinline__ float fast_sig(float x) {
    return 1.0f / (1.0f + __expf(-x));
}
__device__ __forceinline__ float fast_tanh(float x) {
    float ax = fabsf(x);
    float e  = __expf(-2.0f * ax);
    float t  = 1.0f - 2.0f * e / (1.0f + e);
    return copysignf(t, x);
}

// amdgpu_waves_per_eu(1,1): LDS (99 KiB dynamic) limits us to 1 block/CU =
// 1 wave/EU anyway, but the RA can't see dynamic LDS and targets 8 waves/EU
// (<=64 VGPRs -> whh[64] spilled/re-fetched from L2 every step). This
// attribute sets the RA occupancy target to reality -> 512-VGPR budget.
extern "C" __global__ void __launch_bounds__(256, 1)
__attribute__((amdgpu_waves_per_eu(1, 1)))
lstm_fused_kernel(const float* __restrict__ x,
                  const float* __restrict__ w_ih,
                  const float* __restrict__ w_hh,
                  const float* __restrict__ b_ih,
                  const float* __restrict__ b_hh,
                  const float* __restrict__ fc_w,
                  const float* __restrict__ fc_b,
                  float* __restrict__ out)
{
    extern __shared__ float smem[];
    float* xlds = smem;                    // Tn*In = 24576 floats (96 KiB)
    float* act0 = smem + Tn * In;          // 256 floats (ping)
    float* act1 = act0 + Gn;               // 256 floats (pong)
    float* hball = act1 + Gn;              // 4*64 floats (per-wave private h)

    const int tid  = threadIdx.x;          // 0..255 == gate row
    const int lane = tid & 63;
    const int wid  = tid >> 6;             // 0:i 1:f 2:g 3:o
    const int b    = blockIdx.x;

    float* hb = hball + wid * Hn;          // this wave's private h copy

    // ---- stage entire x row into LDS (coalesced float4) ----
    {
        const float4* xsrc = (const float4*)(x + (size_t)b * Tn * In);
        float4* xdst = (float4*)xlds;
        constexpr int NV = Tn * In / 4;    // 6144
        for (int idx = tid; idx < NV; idx += 256) xdst[idx] = xsrc[idx];
    }

    // ---- per-thread weights in registers, pinned via opaque asm anchors ----
    float wih[In];
    {
        const float4* wr = (const float4*)(w_ih + tid * In);
        float4 v0 = wr[0], v1 = wr[1], v2 = wr[2];
        wih[0]=v0.x; wih[1]=v0.y; wih[2]=v0.z;  wih[3]=v0.w;
        wih[4]=v1.x; wih[5]=v1.y; wih[6]=v1.z;  wih[7]=v1.w;
        wih[8]=v2.x; wih[9]=v2.y; wih[10]=v2.z; wih[11]=v2.w;
        #pragma unroll
        for (int j = 0; j < 3; ++j)
            asm volatile("" : "+v"(wih[4*j+0]), "+v"(wih[4*j+1]),
                              "+v"(wih[4*j+2]), "+v"(wih[4*j+3]));
    }
    float whh[Hn];
    {
        const float4* wr = (const float4*)(w_hh + tid * Hn);
        #pragma unroll
        for (int j = 0; j < Hn / 4; ++j) {
            float4 v = wr[j];
            whh[4*j+0]=v.x; whh[4*j+1]=v.y; whh[4*j+2]=v.z; whh[4*j+3]=v.w;
        }
        #pragma unroll
        for (int j = 0; j < Hn / 4; ++j)
            asm volatile("" : "+v"(whh[4*j+0]), "+v"(whh[4*j+1]),
                              "+v"(whh[4*j+2]), "+v"(whh[4*j+3]));
    }
    const float bias = b_ih[tid] + b_hh[tid];
    const float fcw  = fc_w[lane];
    const float fcb  = fc_b[0];

    float c = 0.0f;                        // lane holds c[lane]; replicated per wave
    hb[lane] = 0.0f;                       // own private h copy (h_0 = 0)
    __syncthreads();                       // xlds staged + all init visible

    float* outb = out + (size_t)b * Tn;

    for (int T0 = 0; T0 < Tn; T0 += CHUNK) {
        float p[CHUNK];                    // h history, statically indexed
        #pragma unroll
        for (int s = 0; s < CHUNK; ++s) {
            const int t = T0 + s;
            float* actw = (s & 1) ? act1 : act0;   // compile-time ping-pong

            // ---- phase A: gate pre-activation (x_t from LDS, h from OWN hbuf) ----
            float a0 = bias, a1 = 0.f, a2 = 0.f, a3 = 0.f;
            {
                const float4* xt4 = (const float4*)(xlds + t * In);
                float4 x0 = xt4[0], x1 = xt4[1], x2 = xt4[2];
                a0 = fmaf(x0.x, wih[0],  a0);  a1 = fmaf(x0.y, wih[1],  a1);
                a2 = fmaf(x0.z, wih[2],  a2);  a3 = fmaf(x0.w, wih[3],  a3);
                a0 = fmaf(x1.x, wih[4],  a0);  a1 = fmaf(x1.y, wih[5],  a1);
                a2 = fmaf(x1.z, wih[6],  a2);  a3 = fmaf(x1.w, wih[7],  a3);
                a0 = fmaf(x2.x, wih[8],  a0);  a1 = fmaf(x2.y, wih[9],  a1);
                a2 = fmaf(x2.z, wih[10], a2);  a3 = fmaf(x2.w, wih[11], a3);
            }
            {
                const float4* h4 = (const float4*)hb;  // uniform addr: broadcast reads
                #pragma unroll
                for (int j = 0; j < Hn / 4; ++j) {
                    float4 hv = h4[j];
                    a0 = fmaf(hv.x, whh[4*j+0], a0);
                    a1 = fmaf(hv.y, whh[4*j+1], a1);
                    a2 = fmaf(hv.z, whh[4*j+2], a2);
                    a3 = fmaf(hv.w, whh[4*j+3], a3);
                }
            }
            float gate = (a0 + a1) + (a2 + a3);
            float act  = (wid == 2) ? fast_tanh(gate) : fast_sig(gate);
            actw[tid] = act;
            __syncthreads();               // the ONE barrier per step

            // ---- phase B: every wave redundantly updates c/h for its lane ----
            float iv = actw[lane];
            float fv = actw[64 + lane];
            float gv = actw[128 + lane];
            float ov = actw[192 + lane];
            c = fmaf(fv, c, iv * gv);
            float h = ov * fast_tanh(c);
            p[s] = h;
            hb[lane] = h;                  // own copy only; no cross-wave hazard
            asm volatile("s_waitcnt lgkmcnt(0)" ::: "memory");
        }

        // ---- fc flush: wave w reduces steps [4w, 4w+4) of this chunk ----
        float q0, q1, q2, q3;
        if      (wid == 0) { q0 = p[0];  q1 = p[1];  q2 = p[2];  q3 = p[3];  }
        else if (wid == 1) { q0 = p[4];  q1 = p[5];  q2 = p[6];  q3 = p[7];  }
        else if (wid == 2) { q0 = p[8];  q1 = p[9];  q2 = p[10]; q3 = p[11]; }
        else               { q0 = p[12]; q1 = p[13]; q2 = p[14]; q3 = p[15]; }
        q0 *= fcw; q1 *= fcw; q2 *= fcw; q3 *= fcw;
        #pragma unroll
        for (int off = 32; off; off >>= 1) {
            q0 += __shfl_xor(q0, off, 64);
            q1 += __shfl_xor(q1, off, 64);
            q2 += __shfl_xor(q2, off, 64);
            q3 += __shfl_xor(q3, off, 64);
        }
        if (lane == 0) {
            float4 o4;
            o4.x = q0 + fcb; o4.y = q1 + fcb; o4.z = q2 + fcb; o4.w = q3 + fcb;
            *(float4*)(outb + T0 + 4 * wid) = o4;   // fire-and-forget
        }
    }
}

extern "C" void kernel_launch(void* const* d_in, const int* in_sizes, int n_in,
                              void* d_out, int out_size, void* d_ws, size_t ws_size,
                              hipStream_t stream) {
    const float* x    = (const float*)d_in[0];
    const float* w_ih = (const float*)d_in[1];
    const float* w_hh = (const float*)d_in[2];
    const float* b_ih = (const float*)d_in[3];
    const float* b_hh = (const float*)d_in[4];
    const float* fc_w = (const float*)d_in[5];
    const float* fc_b = (const float*)d_in[6];
    float* out = (float*)d_out;

    // xlds + 2*act + 4*hbuf
    size_t shmem = (size_t)(Tn * In + 2 * Gn + 4 * Hn) * sizeof(float); // ~99 KiB
    hipFuncSetAttribute((const void*)lstm_fused_kernel,
                        hipFuncAttributeMaxDynamicSharedMemorySize, (int)shmem);

    lstm_fused_kernel<<<Bn, 256, shmem, stream>>>(x, w_ih, w_hh, b_ih, b_hh,
                                                  fc_w, fc_b, out);
}

// Round 8
// 1243.158 us; speedup vs baseline: 1.3753x; 1.2059x over previous
//
#include <hip/hip_runtime.h>

// Problem constants (from reference): B=256, T=2048, I=12, H=64
constexpr int Bn = 256;
constexpr int Tn = 2048;
constexpr int In = 12;
constexpr int Hn = 64;
constexpr int Gn = 4 * Hn;   // 256 gates
constexpr int TCH = 1024;    // timesteps staged per half (48 KiB)
constexpr int CHUNK = 16;    // fc-flush granularity (register h-history depth)

__device__ __forceinline__ float fast_sig(float x) {
    return 1.0f / (1.0f + __expf(-x));
}
__device__ __forceinline__ float fast_tanh(float x) {
    float ax = fabsf(x);
    float e  = __expf(-2.0f * ax);
    float t  = 1.0f - 2.0f * e / (1.0f + e);
    return copysignf(t, x);
}

// STATIC shared memory, 56320 B total. This is deliberate: the AMDGPU backend
// derives its register-allocation occupancy target from *visible* LDS usage.
// 56320 B -> floor(163840/56320) = 2 blocks/CU -> 2 waves/EU -> 256-VGPR
// budget, so whh[64]+wih[12]+p[16] (~120 VGPRs) stays register-resident.
// (With dynamic LDS the backend assumed 8 waves/EU -> 64-VGPR cap -> whh was
// re-fetched from L2 every step: rounds 5-7 all showed VGPR_Count=60,
// ~1850 cyc/step == the L2-refetch arithmetic.)
extern "C" __global__ void __launch_bounds__(256, 1)
lstm_fused_kernel(const float* __restrict__ x,
                  const float* __restrict__ w_ih,
                  const float* __restrict__ w_hh,
                  const float* __restrict__ b_ih,
                  const float* __restrict__ b_hh,
                  const float* __restrict__ fc_w,
                  const float* __restrict__ fc_b,
                  float* __restrict__ out)
{
    __shared__ __align__(16) float xbuf[TCH * In];  // 12288 floats, 48 KiB
    __shared__ float act[2][768];                   // ping-pong (padded)
    __shared__ float hball[4 * Hn];                 // per-wave private h copies

    const int tid  = threadIdx.x;          // 0..255 == gate row
    const int lane = tid & 63;
    const int wid  = tid >> 6;             // 0:i 1:f 2:g 3:o
    const int b    = blockIdx.x;

    float* hb = hball + wid * Hn;          // this wave's private h copy

    // ---- stage first half of x row into LDS (coalesced float4) ----
    const float4* xsrc4 = (const float4*)(x + (size_t)b * Tn * In);
    {
        float4* xdst = (float4*)xbuf;
        #pragma unroll
        for (int k = 0; k < TCH * In / 4 / 256; ++k)     // 12 iters
            xdst[tid + k * 256] = xsrc4[tid + k * 256];
    }

    // ---- per-thread weights in registers ----
    float wih[In];
    {
        const float4* wr = (const float4*)(w_ih + tid * In);
        float4 v0 = wr[0], v1 = wr[1], v2 = wr[2];
        wih[0]=v0.x; wih[1]=v0.y; wih[2]=v0.z;  wih[3]=v0.w;
        wih[4]=v1.x; wih[5]=v1.y; wih[6]=v1.z;  wih[7]=v1.w;
        wih[8]=v2.x; wih[9]=v2.y; wih[10]=v2.z; wih[11]=v2.w;
    }
    float whh[Hn];
    {
        const float4* wr = (const float4*)(w_hh + tid * Hn);
        #pragma unroll
        for (int j = 0; j < Hn / 4; ++j) {
            float4 v = wr[j];
            whh[4*j+0]=v.x; whh[4*j+1]=v.y; whh[4*j+2]=v.z; whh[4*j+3]=v.w;
        }
        // Anchors: values become opaque asm results -> cannot be
        // rematerialized from global inside the t-loop.
        #pragma unroll
        for (int j = 0; j < Hn / 4; ++j)
            asm volatile("" : "+v"(whh[4*j+0]), "+v"(whh[4*j+1]),
                              "+v"(whh[4*j+2]), "+v"(whh[4*j+3]));
    }
    const float bias = b_ih[tid] + b_hh[tid];
    const float fcw  = fc_w[lane];
    const float fcb  = fc_b[0];

    float c = 0.0f;                        // lane holds c[lane]; replicated per wave
    hb[lane] = 0.0f;                       // own private h copy (h_0 = 0)
    __syncthreads();                       // staging + init visible

    float* outb = out + (size_t)b * Tn;

    for (int T0 = 0; T0 < Tn; T0 += CHUNK) {
        // ---- refresh x staging at the halfway point ----
        if (T0 == TCH) {
            // all waves are past step TCH-1's barrier, so xbuf is dead here
            float4* xdst = (float4*)xbuf;
            #pragma unroll
            for (int k = 0; k < TCH * In / 4 / 256; ++k)
                xdst[tid + k * 256] = xsrc4[3072 + tid + k * 256];
            __syncthreads();
        }

        float p[CHUNK];                    // h history, statically indexed
        #pragma unroll
        for (int s = 0; s < CHUNK; ++s) {
            const int t  = T0 + s;
            const int tl = t & (TCH - 1);          // index within staged half
            float* actw = act[s & 1];              // compile-time ping-pong

            // ---- phase A: gate pre-activation ----
            float a0 = bias, a1 = 0.f, a2 = 0.f, a3 = 0.f;
            {
                const float4* xt4 = (const float4*)(xbuf + tl * In);
                float4 x0 = xt4[0], x1 = xt4[1], x2 = xt4[2];
                a0 = fmaf(x0.x, wih[0],  a0);  a1 = fmaf(x0.y, wih[1],  a1);
                a2 = fmaf(x0.z, wih[2],  a2);  a3 = fmaf(x0.w, wih[3],  a3);
                a0 = fmaf(x1.x, wih[4],  a0);  a1 = fmaf(x1.y, wih[5],  a1);
                a2 = fmaf(x1.z, wih[6],  a2);  a3 = fmaf(x1.w, wih[7],  a3);
                a0 = fmaf(x2.x, wih[8],  a0);  a1 = fmaf(x2.y, wih[9],  a1);
                a2 = fmaf(x2.z, wih[10], a2);  a3 = fmaf(x2.w, wih[11], a3);
            }
            {
                const float4* h4 = (const float4*)hb;  // uniform addr: broadcast
                #pragma unroll
                for (int j = 0; j < Hn / 4; ++j) {
                    float4 hv = h4[j];
                    a0 = fmaf(hv.x, whh[4*j+0], a0);
                    a1 = fmaf(hv.y, whh[4*j+1], a1);
                    a2 = fmaf(hv.z, whh[4*j+2], a2);
                    a3 = fmaf(hv.w, whh[4*j+3], a3);
                }
            }
            float gate = (a0 + a1) + (a2 + a3);
            float a    = (wid == 2) ? fast_tanh(gate) : fast_sig(gate);
            actw[tid] = a;
            __syncthreads();               // the ONE barrier per step

            // ---- phase B: every wave redundantly updates c/h for its lane ----
            float iv = actw[lane];
            float fv = actw[64 + lane];
            float gv = actw[128 + lane];
            float ov = actw[192 + lane];
            c = fmaf(fv, c, iv * gv);
            float h = ov * fast_tanh(c);
            p[s] = h;
            hb[lane] = h;                  // own copy only; no cross-wave hazard
            asm volatile("s_waitcnt lgkmcnt(0)" ::: "memory");
        }

        // ---- fc flush: wave w reduces steps [4w, 4w+4) of this chunk ----
        float q0, q1, q2, q3;
        if      (wid == 0) { q0 = p[0];  q1 = p[1];  q2 = p[2];  q3 = p[3];  }
        else if (wid == 1) { q0 = p[4];  q1 = p[5];  q2 = p[6];  q3 = p[7];  }
        else if (wid == 2) { q0 = p[8];  q1 = p[9];  q2 = p[10]; q3 = p[11]; }
        else               { q0 = p[12]; q1 = p[13]; q2 = p[14]; q3 = p[15]; }
        q0 *= fcw; q1 *= fcw; q2 *= fcw; q3 *= fcw;
        #pragma unroll
        for (int off = 32; off; off >>= 1) {
            q0 += __shfl_xor(q0, off, 64);
            q1 += __shfl_xor(q1, off, 64);
            q2 += __shfl_xor(q2, off, 64);
            q3 += __shfl_xor(q3, off, 64);
        }
        if (lane == 0) {
            float4 o4;
            o4.x = q0 + fcb; o4.y = q1 + fcb; o4.z = q2 + fcb; o4.w = q3 + fcb;
            *(float4*)(outb + T0 + 4 * wid) = o4;   // fire-and-forget
        }
    }
}

extern "C" void kernel_launch(void* const* d_in, const int* in_sizes, int n_in,
                              void* d_out, int out_size, void* d_ws, size_t ws_size,
                              hipStream_t stream) {
    const float* x    = (const float*)d_in[0];
    const float* w_ih = (const float*)d_in[1];
    const float* w_hh = (const float*)d_in[2];
    const float* b_ih = (const float*)d_in[3];
    const float* b_hh = (const float*)d_in[4];
    const float* fc_w = (const float*)d_in[5];
    const float* fc_b = (const float*)d_in[6];
    float* out = (float*)d_out;

    lstm_fused_kernel<<<Bn, 256, 0, stream>>>(x, w_ih, w_hh, b_ih, b_hh,
                                              fc_w, fc_b, out);
}

// Round 9
// 1013.089 us; speedup vs baseline: 1.6876x; 1.2271x over previous
//
#include <hip/hip_runtime.h>

// Problem constants (from reference): B=256, T=2048, I=12, H=64
constexpr int Bn = 256;
constexpr int Tn = 2048;
constexpr int In = 12;
constexpr int Hn = 64;
constexpr int TCH = 1024;    // timesteps staged per half (48 KiB)
constexpr int CHUNK = 16;    // fc-flush granularity == hist ring depth

__device__ __forceinline__ float frcp(float v) { return __builtin_amdgcn_rcpf(v); }

// Thread mapping (the round-9 restructure):
//   wave w (0..3) owns h-indices j in [16w, 16w+16)
//   lane = 16*g + i16 : g = gate type (0:i 1:f 2:g 3:o), i16 = h-offset
//   => i/f/g/o for one h-index live in ONE wave -> act exchange is 3 shfls,
//      not an LDS round-trip + barrier. Only ONE barrier per step (h publish).
extern "C" __global__ void __launch_bounds__(256, 1)
lstm_fused_kernel(const float* __restrict__ x,
                  const float* __restrict__ w_ih,
                  const float* __restrict__ w_hh,
                  const float* __restrict__ b_ih,
                  const float* __restrict__ b_hh,
                  const float* __restrict__ fc_w,
                  const float* __restrict__ fc_b,
                  float* __restrict__ out)
{
    __shared__ __align__(16) float xbuf[TCH * In];     // 48 KiB (half of x row)
    __shared__ __align__(16) float hist[CHUNK][Hn];    // 4 KiB h ring buffer

    const int tid  = threadIdx.x;
    const int lane = tid & 63;
    const int w    = tid >> 6;          // wave id 0..3
    const int i16  = lane & 15;         // h-offset within wave's 16
    const int g    = lane >> 4;         // gate type 0:i 1:f 2:g 3:o
    const int j    = w * 16 + i16;      // owned h index (g==0 lanes)
    const int row  = g * 64 + j;        // row in w_ih / w_hh / biases
    const int b    = blockIdx.x;

    // ---- stage first half of x row into LDS (coalesced float4) ----
    const float4* xsrc4 = (const float4*)(x + (size_t)b * Tn * In);
    {
        float4* xdst = (float4*)xbuf;
        #pragma unroll
        for (int k = 0; k < TCH * In / 4 / 256; ++k)     // 12 iters
            xdst[tid + k * 256] = xsrc4[tid + k * 256];
    }

    // ---- per-thread weights in registers (anchored against re-fetch) ----
    float wih[In];
    {
        const float4* wr = (const float4*)(w_ih + row * In);   // 48B-aligned
        float4 v0 = wr[0], v1 = wr[1], v2 = wr[2];
        wih[0]=v0.x; wih[1]=v0.y; wih[2]=v0.z;  wih[3]=v0.w;
        wih[4]=v1.x; wih[5]=v1.y; wih[6]=v1.z;  wih[7]=v1.w;
        wih[8]=v2.x; wih[9]=v2.y; wih[10]=v2.z; wih[11]=v2.w;
        #pragma unroll
        for (int k = 0; k < 3; ++k)
            asm volatile("" : "+v"(wih[4*k+0]), "+v"(wih[4*k+1]),
                              "+v"(wih[4*k+2]), "+v"(wih[4*k+3]));
    }
    float whh[Hn];
    {
        const float4* wr = (const float4*)(w_hh + row * Hn);
        #pragma unroll
        for (int k = 0; k < Hn / 4; ++k) {
            float4 v = wr[k];
            whh[4*k+0]=v.x; whh[4*k+1]=v.y; whh[4*k+2]=v.z; whh[4*k+3]=v.w;
        }
        #pragma unroll
        for (int k = 0; k < Hn / 4; ++k)
            asm volatile("" : "+v"(whh[4*k+0]), "+v"(whh[4*k+1]),
                              "+v"(whh[4*k+2]), "+v"(whh[4*k+3]));
    }
    const float bias = b_ih[row] + b_hh[row];
    // Branchless activation constants: act = m*sigma(m*a) - (m-1)
    //   g!=2 : m=1 -> sigma(a);   g==2 : m=2 -> 2*sigma(2a)-1 = tanh(a)
    const float m    = (g == 2) ? 2.0f : 1.0f;
    const float madd = (g == 2) ? -1.0f : 0.0f;
    // fc flush constants: thread covers j4 = 4*(tid&15) .. +3 of step tid>>4
    const int   fq   = tid & 15;
    const int   fs   = tid >> 4;
    const float4 fw4 = *(const float4*)(fc_w + 4 * fq);
    const float fcb  = fc_b[0];

    float c = 0.0f;                      // g==0 lanes: cell state for index j
    if (tid < Hn) hist[CHUNK - 1][tid] = 0.0f;   // h_{-1} = 0
    __syncthreads();

    float* outb = out + (size_t)b * Tn;

    for (int T0 = 0; T0 < Tn; T0 += CHUNK) {
        // ---- refresh x staging at the halfway point (xbuf dead here) ----
        if (T0 == TCH) {
            float4* xdst = (float4*)xbuf;
            #pragma unroll
            for (int k = 0; k < TCH * In / 4 / 256; ++k)
                xdst[tid + k * 256] = xsrc4[3072 + tid + k * 256];
            __syncthreads();
        }

        #pragma unroll
        for (int s = 0; s < CHUNK; ++s) {
            const int tl = (T0 + s) & (TCH - 1);       // x index in staged half

            // ---- phase A: gate pre-activation (uniform LDS reads: broadcast) ----
            float a0 = bias, a1 = 0.f, a2 = 0.f, a3 = 0.f;
            {
                const float4* xt4 = (const float4*)(xbuf + tl * In);
                float4 x0 = xt4[0], x1 = xt4[1], x2 = xt4[2];
                a0 = fmaf(x0.x, wih[0],  a0);  a1 = fmaf(x0.y, wih[1],  a1);
                a2 = fmaf(x0.z, wih[2],  a2);  a3 = fmaf(x0.w, wih[3],  a3);
                a0 = fmaf(x1.x, wih[4],  a0);  a1 = fmaf(x1.y, wih[5],  a1);
                a2 = fmaf(x1.z, wih[6],  a2);  a3 = fmaf(x1.w, wih[7],  a3);
                a0 = fmaf(x2.x, wih[8],  a0);  a1 = fmaf(x2.y, wih[9],  a1);
                a2 = fmaf(x2.z, wih[10], a2);  a3 = fmaf(x2.w, wih[11], a3);
            }
            {
                const float4* h4 = (const float4*)hist[(s + CHUNK - 1) & (CHUNK - 1)];
                #pragma unroll
                for (int k = 0; k < Hn / 4; ++k) {
                    float4 hv = h4[k];
                    a0 = fmaf(hv.x, whh[4*k+0], a0);
                    a1 = fmaf(hv.y, whh[4*k+1], a1);
                    a2 = fmaf(hv.z, whh[4*k+2], a2);
                    a3 = fmaf(hv.w, whh[4*k+3], a3);
                }
            }
            float gate = (a0 + a1) + (a2 + a3);
            // branchless sigmoid/tanh
            float e   = __expf(-m * gate);
            float act = fmaf(m, frcp(1.0f + e), madd);

            // ---- intra-wave gate exchange: 3 independent shfls ----
            float fv = __shfl_down(act, 16, 64);
            float gv = __shfl_down(act, 32, 64);
            float ov = __shfl_down(act, 48, 64);

            // ---- g==0 lanes: c/h update + publish h ----
            if (g == 0) {
                c = fmaf(fv, c, act * gv);             // act == iv here
                float e2 = __expf(-2.0f * c);
                float th = fmaf(2.0f, frcp(1.0f + e2), -1.0f);
                hist[s][j] = ov * th;
            }
            __syncthreads();               // the ONE barrier per step
        }

        // ---- fc flush: 256 threads reduce hist[16][64] -> 16 outputs ----
        {
            const float4 hv = *(const float4*)(hist[fs] + 4 * fq);
            float pp = hv.x * fw4.x + hv.y * fw4.y + hv.z * fw4.z + hv.w * fw4.w;
            #pragma unroll
            for (int off = 8; off; off >>= 1)
                pp += __shfl_xor(pp, off, 16);
            if (fq == 0) outb[T0 + fs] = pp + fcb;
        }
        __syncthreads();                   // protect hist before next chunk
    }
}

extern "C" void kernel_launch(void* const* d_in, const int* in_sizes, int n_in,
                              void* d_out, int out_size, void* d_ws, size_t ws_size,
                              hipStream_t stream) {
    const float* x    = (const float*)d_in[0];
    const float* w_ih = (const float*)d_in[1];
    const float* w_hh = (const float*)d_in[2];
    const float* b_ih = (const float*)d_in[3];
    const float* b_hh = (const float*)d_in[4];
    const float* fc_w = (const float*)d_in[5];
    const float* fc_b = (const float*)d_in[6];
    float* out = (float*)d_out;

    lstm_fused_kernel<<<Bn, 256, 0, stream>>>(x, w_ih, w_hh, b_ih, b_hh,
                                              fc_w, fc_b, out);
}

// Round 10
// 953.619 us; speedup vs baseline: 1.7928x; 1.0624x over previous
//
#include <hip/hip_runtime.h>

// Problem constants (from reference): B=256, T=2048, I=12, H=64
constexpr int Bn = 256;
constexpr int Tn = 2048;
constexpr int In = 12;
constexpr int Hn = 64;
constexpr int TCH = 1024;    // timesteps staged per half (48 KiB)
constexpr int CHUNK = 16;    // fc-flush granularity == hist ring depth

constexpr float LOG2E = 1.44269504088896340736f;

__device__ __forceinline__ float frcp(float v) { return __builtin_amdgcn_rcpf(v); }

// quad_perm DPP: cross-lane move within each group of 4 lanes, pure VALU.
template <int CTRL>
__device__ __forceinline__ float dppq(float v) {
    int i = __float_as_int(v);
    i = __builtin_amdgcn_mov_dpp(i, CTRL, 0xF, 0xF, false);
    return __int_as_float(i);
}

// Thread mapping (round-10): lane = 4*i16 + g
//   g   = lane & 3   : gate type (0:i 1:f 2:g 3:o)
//   i16 = lane >> 2  : h-offset within the wave's 16 indices
//   j   = 16*wave + i16 : owned h index
// The 4 gates of h-index j sit in adjacent lanes 4*i16..4*i16+3 of one wave,
// so the i/f/g/o exchange is 3 quad_perm DPP ops (no LDS, no barrier).
extern "C" __global__ void __launch_bounds__(256, 1)
lstm_fused_kernel(const float* __restrict__ x,
                  const float* __restrict__ w_ih,
                  const float* __restrict__ w_hh,
                  const float* __restrict__ b_ih,
                  const float* __restrict__ b_hh,
                  const float* __restrict__ fc_w,
                  const float* __restrict__ fc_b,
                  float* __restrict__ out)
{
    __shared__ __align__(16) float xbuf[TCH * In];      // 48 KiB (half of x row)
    __shared__ __align__(16) float hist[2][CHUNK * Hn]; // 2 x 4 KiB ping-pong

    const int tid  = threadIdx.x;
    const int lane = tid & 63;
    const int w    = tid >> 6;          // wave id 0..3
    const int g    = lane & 3;          // gate type
    const int i16  = lane >> 2;         // 0..15
    const int j    = w * 16 + i16;      // owned h index (g==0 lanes)
    const int row  = g * 64 + j;        // row in w_ih / w_hh / biases
    const int b    = blockIdx.x;

    // ---- stage first half of x row into LDS (coalesced float4) ----
    const float4* xsrc4 = (const float4*)(x + (size_t)b * Tn * In);
    {
        float4* xdst = (float4*)xbuf;
        #pragma unroll
        for (int k = 0; k < TCH * In / 4 / 256; ++k)     // 12 iters
            xdst[tid + k * 256] = xsrc4[tid + k * 256];
    }

    // ---- per-thread weights in registers (anchored against re-fetch) ----
    float wih[In];
    {
        const float4* wr = (const float4*)(w_ih + row * In);   // 48B-aligned
        float4 v0 = wr[0], v1 = wr[1], v2 = wr[2];
        wih[0]=v0.x; wih[1]=v0.y; wih[2]=v0.z;  wih[3]=v0.w;
        wih[4]=v1.x; wih[5]=v1.y; wih[6]=v1.z;  wih[7]=v1.w;
        wih[8]=v2.x; wih[9]=v2.y; wih[10]=v2.z; wih[11]=v2.w;
        #pragma unroll
        for (int k = 0; k < 3; ++k)
            asm volatile("" : "+v"(wih[4*k+0]), "+v"(wih[4*k+1]),
                              "+v"(wih[4*k+2]), "+v"(wih[4*k+3]));
    }
    float whh[Hn];
    {
        const float4* wr = (const float4*)(w_hh + row * Hn);
        #pragma unroll
        for (int k = 0; k < Hn / 4; ++k) {
            float4 v = wr[k];
            whh[4*k+0]=v.x; whh[4*k+1]=v.y; whh[4*k+2]=v.z; whh[4*k+3]=v.w;
        }
        #pragma unroll
        for (int k = 0; k < Hn / 4; ++k)
            asm volatile("" : "+v"(whh[4*k+0]), "+v"(whh[4*k+1]),
                              "+v"(whh[4*k+2]), "+v"(whh[4*k+3]));
    }
    const float bias = b_ih[row] + b_hh[row];
    // act = m * sigma(m*a) - (m-1):  g!=2 -> sigma(a);  g==2 -> tanh(a)
    const float m    = (g == 2) ? 2.0f : 1.0f;
    const float madd = (g == 2) ? -1.0f : 0.0f;
    const float me   = (g == 2) ? (-2.0f * LOG2E) : (-LOG2E); // exp2 scale
    // fc flush constants: thread covers h[4*fq..4*fq+3] of chunk-step fs
    const int   fq   = tid & 15;
    const int   fs   = tid >> 4;
    const float4 fw4 = *(const float4*)(fc_w + 4 * fq);
    const float fcb  = fc_b[0];

    float c = 0.0f;                      // g==0 lanes: cell state for index j
    if (tid < Hn) hist[1][(CHUNK - 1) * Hn + tid] = 0.0f;   // h_{-1} = 0
    __syncthreads();

    float* outb = out + (size_t)b * Tn;

    for (int ci = 0; ci < Tn / CHUNK; ++ci) {
        const int T0 = ci * CHUNK;
        // ---- refresh x staging at the halfway point (xbuf dead here) ----
        if (T0 == TCH) {
            float4* xdst = (float4*)xbuf;
            #pragma unroll
            for (int k = 0; k < TCH * In / 4 / 256; ++k)
                xdst[tid + k * 256] = xsrc4[3072 + tid + k * 256];
            __syncthreads();
        }

        float*       histC = hist[ci & 1];
        const float* histP = hist[(ci & 1) ^ 1];

        #pragma unroll
        for (int s = 0; s < CHUNK; ++s) {
            const int tl = (T0 + s) & (TCH - 1);       // x index in staged half
            const float* hprev = (s == 0) ? (histP + (CHUNK - 1) * Hn)
                                          : (histC + (s - 1) * Hn);

            // ---- phase A: gate pre-activation (uniform LDS reads: broadcast) ----
            float a0 = bias, a1 = 0.f, a2 = 0.f, a3 = 0.f;
            {
                const float4* xt4 = (const float4*)(xbuf + tl * In);
                float4 x0 = xt4[0], x1 = xt4[1], x2 = xt4[2];
                a0 = fmaf(x0.x, wih[0],  a0);  a1 = fmaf(x0.y, wih[1],  a1);
                a2 = fmaf(x0.z, wih[2],  a2);  a3 = fmaf(x0.w, wih[3],  a3);
                a0 = fmaf(x1.x, wih[4],  a0);  a1 = fmaf(x1.y, wih[5],  a1);
                a2 = fmaf(x1.z, wih[6],  a2);  a3 = fmaf(x1.w, wih[7],  a3);
                a0 = fmaf(x2.x, wih[8],  a0);  a1 = fmaf(x2.y, wih[9],  a1);
                a2 = fmaf(x2.z, wih[10], a2);  a3 = fmaf(x2.w, wih[11], a3);
            }
            {
                const float4* h4 = (const float4*)hprev;
                #pragma unroll
                for (int k = 0; k < Hn / 4; ++k) {
                    float4 hv = h4[k];
                    a0 = fmaf(hv.x, whh[4*k+0], a0);
                    a1 = fmaf(hv.y, whh[4*k+1], a1);
                    a2 = fmaf(hv.z, whh[4*k+2], a2);
                    a3 = fmaf(hv.w, whh[4*k+3], a3);
                }
            }
            float gate = (a0 + a1) + (a2 + a3);
            // branchless sigmoid/tanh via native exp2
            float e   = exp2f(me * gate);
            float act = fmaf(m, frcp(1.0f + e), madd);

            // ---- intra-quad gate exchange: 3 quad_perm DPP moves ----
            float fv = dppq<0xB1>(act);   // xor 1
            float gv = dppq<0x4E>(act);   // xor 2
            float ov = dppq<0x1B>(act);   // xor 3

            // ---- g==0 lanes: c/h update + publish h ----
            if (g == 0) {
                c = fmaf(fv, c, act * gv);             // act == iv here
                float e2 = exp2f(-2.0f * LOG2E * c);
                float th = fmaf(2.0f, frcp(1.0f + e2), -1.0f);
                histC[s * Hn + j] = ov * th;
            }
            __syncthreads();               // the ONE barrier per step
        }

        // ---- fc flush: 256 threads reduce histC[16][64] -> 16 outputs ----
        // No trailing barrier: next chunk writes the OTHER hist buffer, and
        // its 16 per-step barriers fence any buffer reuse two chunks out.
        {
            const float4 hv = *(const float4*)(histC + fs * Hn + 4 * fq);
            float pp = hv.x * fw4.x + hv.y * fw4.y + hv.z * fw4.z + hv.w * fw4.w;
            #pragma unroll
            for (int off = 8; off; off >>= 1)
                pp += __shfl_xor(pp, off, 16);
            if (fq == 0) outb[T0 + fs] = pp + fcb;
        }
    }
}

extern "C" void kernel_launch(void* const* d_in, const int* in_sizes, int n_in,
                              void* d_out, int out_size, void* d_ws, size_t ws_size,
                              hipStream_t stream) {
    const float* x    = (const float*)d_in[0];
    const float* w_ih = (const float*)d_in[1];
    const float* w_hh = (const float*)d_in[2];
    const float* b_ih = (const float*)d_in[3];
    const float* b_hh = (const float*)d_in[4];
    const float* fc_w = (const float*)d_in[5];
    const float* fc_b = (const float*)d_in[6];
    float* out = (float*)d_out;

    lstm_fused_kernel<<<Bn, 256, 0, stream>>>(x, w_ih, w_hh, b_ih, b_hh,
                                              fc_w, fc_b, out);
}

// Round 12
// 840.796 us; speedup vs baseline: 2.0334x; 1.1342x over previous
//
#include <hip/hip_runtime.h>

// Problem constants (from reference): B=256, T=2048, I=12, H=64
constexpr int Bn = 256;
constexpr int Tn = 2048;
constexpr int In = 12;
constexpr int Hn = 64;
constexpr int TCH = 512;     // steps per staged x quarter (padded to 16 floats)
constexpr int CHUNK = 16;    // fc-flush granularity == hist ring depth

constexpr float LOG2E = 1.44269504088896340736f;

__device__ __forceinline__ float frcp(float v) { return __builtin_amdgcn_rcpf(v); }

// quad_perm DPP: cross-lane move within each group of 4 lanes, pure VALU.
template <int CTRL>
__device__ __forceinline__ float dppq(float v) {
    int i = __float_as_int(v);
    i = __builtin_amdgcn_mov_dpp(i, CTRL, 0xF, 0xF, false);
    return __int_as_float(i);
}

// Round-11 K-split mapping:
//   PARTIAL phase: wave w owns K-slice h[16w..16w+16) and x[4w..4w+4)
//     (wave 3 x-weights = 0; x padded to 16 floats/step). Lane l computes
//     partial dots for rows 4l..4l+3 over its wave's K-slice -> 80 FMA.
//   REDUCE phase: lane (g = l&3, i16 = l>>2) owns row ro = 64g + 16w + i16.
//     Sums 4 wave-partials + bias, activates, quad-DPP broadcast of i/f/g/o,
//     redundant c/h update per quad. h published intra-wave only:
//     the h values wave w needs next step are exactly the 16 it computed.
extern "C" __global__ void __launch_bounds__(256, 1)
lstm_fused_kernel(const float* __restrict__ x,
                  const float* __restrict__ w_ih,
                  const float* __restrict__ w_hh,
                  const float* __restrict__ b_ih,
                  const float* __restrict__ b_hh,
                  const float* __restrict__ fc_w,
                  const float* __restrict__ fc_b,
                  float* __restrict__ out)
{
    __shared__ __align__(16) float xbuf[TCH * 16];        // 32 KiB (x quarter)
    __shared__ __align__(16) float pbuf[2][4][256];       // 8 KiB partial sums
    __shared__ __align__(16) float hist[2][CHUNK * Hn];   // 8 KiB h ring

    const int tid  = threadIdx.x;
    const int lane = tid & 63;
    const int w    = tid >> 6;          // wave id 0..3
    const int g    = lane & 3;          // gate type 0:i 1:f 2:g 3:o
    const int i16  = lane >> 2;         // 0..15
    const int jown = 16 * w + i16;      // h index owned in reduce phase
    const int ro   = 64 * g + jown;     // output row in reduce phase
    const int b    = blockIdx.x;

    const float4* xsrc4 = (const float4*)(x + (size_t)b * Tn * In);

    // ---- zero the x padding columns (i = 12..15) once ----
    #pragma unroll
    for (int k = 0; k < 8; ++k) {
        int idx = tid + k * 256;                       // 0..2047
        xbuf[(idx >> 2) * 16 + 12 + (idx & 3)] = 0.0f;
    }

    // ---- per-lane weight slices (rows 4*lane..4*lane+3, K-slice of wave) ----
    float whh_s[4][16];
    #pragma unroll
    for (int r = 0; r < 4; ++r) {
        const float4* src = (const float4*)(w_hh + (4 * lane + r) * Hn + 16 * w);
        float4 v0 = src[0], v1 = src[1], v2 = src[2], v3 = src[3];
        whh_s[r][0]=v0.x;  whh_s[r][1]=v0.y;  whh_s[r][2]=v0.z;  whh_s[r][3]=v0.w;
        whh_s[r][4]=v1.x;  whh_s[r][5]=v1.y;  whh_s[r][6]=v1.z;  whh_s[r][7]=v1.w;
        whh_s[r][8]=v2.x;  whh_s[r][9]=v2.y;  whh_s[r][10]=v2.z; whh_s[r][11]=v2.w;
        whh_s[r][12]=v3.x; whh_s[r][13]=v3.y; whh_s[r][14]=v3.z; whh_s[r][15]=v3.w;
    }
    #pragma unroll
    for (int r = 0; r < 4; ++r)
        #pragma unroll
        for (int k = 0; k < 16; k += 4)
            asm volatile("" : "+v"(whh_s[r][k+0]), "+v"(whh_s[r][k+1]),
                              "+v"(whh_s[r][k+2]), "+v"(whh_s[r][k+3]));

    float wih_s[4][4];
    if (w < 3) {
        #pragma unroll
        for (int r = 0; r < 4; ++r) {
            float4 v = *(const float4*)(w_ih + (4 * lane + r) * In + 4 * w);
            wih_s[r][0]=v.x; wih_s[r][1]=v.y; wih_s[r][2]=v.z; wih_s[r][3]=v.w;
        }
    } else {
        #pragma unroll
        for (int r = 0; r < 4; ++r)
            wih_s[r][0]=wih_s[r][1]=wih_s[r][2]=wih_s[r][3]=0.0f;
    }
    #pragma unroll
    for (int r = 0; r < 4; ++r)
        asm volatile("" : "+v"(wih_s[r][0]), "+v"(wih_s[r][1]),
                          "+v"(wih_s[r][2]), "+v"(wih_s[r][3]));

    const float bias = b_ih[ro] + b_hh[ro];
    // act = m * sigma(m*a) - (m-1):  g!=2 -> sigma(a);  g==2 -> tanh(a)
    const float m    = (g == 2) ? 2.0f : 1.0f;
    const float madd = (g == 2) ? -1.0f : 0.0f;
    const float me   = (g == 2) ? (-2.0f * LOG2E) : (-LOG2E);
    // fc flush constants
    const int   fq   = tid & 15;
    const int   fs   = tid >> 4;
    const float4 fw4 = *(const float4*)(fc_w + 4 * fq);
    const float fcb  = fc_b[0];

    float hreg[16];                     // wave's own h slice (broadcast values)
    #pragma unroll
    for (int k = 0; k < 16; ++k) hreg[k] = 0.0f;
    float c = 0.0f;                     // cell state for jown (quad-redundant)

    float* outb = out + (size_t)b * Tn;

    for (int ci = 0; ci < Tn / CHUNK; ++ci) {
        const int T0 = ci * CHUNK;

        // ---- stage x quarter (previous quarter fully consumed pre-barrier) ----
        if ((T0 & (TCH - 1)) == 0) {
            const int qtr = T0 >> 9;
            #pragma unroll
            for (int k = 0; k < 6; ++k) {
                int li  = tid + k * 256;              // 0..1535 (local float4)
                int t_l = li / 3;                     // local step
                int i4  = li % 3;                     // float4 slot within row
                ((float4*)xbuf)[t_l * 4 + i4] = xsrc4[qtr * 1536 + li];
            }
            __syncthreads();
        }

        float* histC = hist[ci & 1];

        #pragma unroll
        for (int s = 0; s < CHUNK; ++s) {
            const int tl = (T0 + s) & (TCH - 1);

            // ---- partial phase: rows 4*lane..4*lane+3 over wave's K-slice ----
            const float4 xv = *(const float4*)(xbuf + tl * 16 + 4 * w);
            float p0, p1, p2, p3;
            p0 = xv.x * wih_s[0][0];  p1 = xv.x * wih_s[1][0];
            p2 = xv.x * wih_s[2][0];  p3 = xv.x * wih_s[3][0];
            p0 = fmaf(xv.y, wih_s[0][1], p0);  p1 = fmaf(xv.y, wih_s[1][1], p1);
            p2 = fmaf(xv.y, wih_s[2][1], p2);  p3 = fmaf(xv.y, wih_s[3][1], p3);
            p0 = fmaf(xv.z, wih_s[0][2], p0);  p1 = fmaf(xv.z, wih_s[1][2], p1);
            p2 = fmaf(xv.z, wih_s[2][2], p2);  p3 = fmaf(xv.z, wih_s[3][2], p3);
            p0 = fmaf(xv.w, wih_s[0][3], p0);  p1 = fmaf(xv.w, wih_s[1][3], p1);
            p2 = fmaf(xv.w, wih_s[2][3], p2);  p3 = fmaf(xv.w, wih_s[3][3], p3);
            #pragma unroll
            for (int kk = 0; kk < 16; ++kk) {
                p0 = fmaf(hreg[kk], whh_s[0][kk], p0);
                p1 = fmaf(hreg[kk], whh_s[1][kk], p1);
                p2 = fmaf(hreg[kk], whh_s[2][kk], p2);
                p3 = fmaf(hreg[kk], whh_s[3][kk], p3);
            }
            float4 pv; pv.x = p0; pv.y = p1; pv.z = p2; pv.w = p3;
            *(float4*)(&pbuf[s & 1][w][4 * lane]) = pv;
            __syncthreads();               // the ONE barrier per step

            // ---- reduce phase: own row ro ----
            const float* pb = &pbuf[s & 1][0][0];
            float a = (pb[ro] + pb[256 + ro]) + (pb[512 + ro] + pb[768 + ro]) + bias;
            float e   = exp2f(me * a);
            float act = fmaf(m, frcp(1.0f + e), madd);

            // quad broadcasts: every lane gets labeled i/f/g/o
            float iv = dppq<0x00>(act);
            float fv = dppq<0x55>(act);
            float gv = dppq<0xAA>(act);
            float ov = dppq<0xFF>(act);

            c = fmaf(fv, c, iv * gv);                  // redundant per quad
            float e2 = exp2f(-2.0f * LOG2E * c);
            float h  = ov * fmaf(2.0f, frcp(1.0f + e2), -1.0f);

            if (g == 0) histC[s * Hn + jown] = h;      // publish own h
            asm volatile("s_waitcnt lgkmcnt(0)" ::: "memory");
            // reload OWN wave's slice (intra-wave: no barrier needed)
            const float4* h4 = (const float4*)(histC + s * Hn + 16 * w);
            float4 h0 = h4[0], h1 = h4[1], h2 = h4[2], h3 = h4[3];
            hreg[0]=h0.x;  hreg[1]=h0.y;  hreg[2]=h0.z;  hreg[3]=h0.w;
            hreg[4]=h1.x;  hreg[5]=h1.y;  hreg[6]=h1.z;  hreg[7]=h1.w;
            hreg[8]=h2.x;  hreg[9]=h2.y;  hreg[10]=h2.z; hreg[11]=h2.w;
            hreg[12]=h3.x; hreg[13]=h3.y; hreg[14]=h3.z; hreg[15]=h3.w;
        }

        // ---- fc flush (needs all waves' hist writes of this chunk) ----
        __syncthreads();
        {
            const float4 hv = *(const float4*)(histC + fs * Hn + 4 * fq);
            float pp = hv.x * fw4.x + hv.y * fw4.y + hv.z * fw4.z + hv.w * fw4.w;
            #pragma unroll
            for (int off = 8; off; off >>= 1)
                pp += __shfl_xor(pp, off, 16);
            if (fq == 0) outb[T0 + fs] = pp + fcb;
        }
    }
}

extern "C" void kernel_launch(void* const* d_in, const int* in_sizes, int n_in,
                              void* d_out, int out_size, void* d_ws, size_t ws_size,
                              hipStream_t stream) {
    const float* x    = (const float*)d_in[0];
    const float* w_ih = (const float*)d_in[1];
    const float* w_hh = (const float*)d_in[2];
    const float* b_ih = (const float*)d_in[3];
    const float* b_hh = (const float*)d_in[4];
    const float* fc_w = (const float*)d_in[5];
    const float* fc_b = (const float*)d_in[6];
    float* out = (float*)d_out;

    lstm_fused_kernel<<<Bn, 256, 0, stream>>>(x, w_ih, w_hh, b_ih, b_hh,
                                              fc_w, fc_b, out);
}

// Round 14
// 713.858 us; speedup vs baseline: 2.3950x; 1.1778x over previous
//
#include <hip/hip_runtime.h>

// Problem constants (from reference): B=256, T=2048, I=12, H=64
constexpr int Bn = 256;
constexpr int Tn = 2048;
constexpr int In = 12;
constexpr int Hn = 64;
constexpr int TCH = 512;     // steps per staged x quarter (padded to 16 floats)
constexpr int CHUNK = 16;    // fc-flush granularity == hist depth

constexpr float LOG2E = 1.44269504088896340736f;

__device__ __forceinline__ float frcp(float v) { return __builtin_amdgcn_rcpf(v); }

// quad_perm DPP: cross-lane move within each group of 4 lanes, pure VALU.
template <int CTRL>
__device__ __forceinline__ float dppq(float v) {
    int i = __float_as_int(v);
    i = __builtin_amdgcn_mov_dpp(i, CTRL, 0xF, 0xF, false);
    return __int_as_float(i);
}
// readlane: SGPR broadcast of lane L's value (ignores exec). The h values are
// quad-redundant, so lane 4k holds h[16w+k]; 16 readlanes replace the
// LDS publish/reload round-trip on the recurrence critical path.
__device__ __forceinline__ float rdl(float v, int l) {
    return __int_as_float(__builtin_amdgcn_readlane(__float_as_int(v), l));
}

// Round-13 mapping (K-split as round 12):
//   PARTIAL: wave w owns K-slice h[16w..16w+16) + x[4w..4w+4) (wave3 x-wts=0).
//     Lane l computes partial dots for rows 4l..4l+3 -> one b128 to pbuf.
//   pbuf layout [wv][w_owner][gate][i16]:
//     write base = ((l>>2)&3)*64 + (l>>4)*16 + 4*(l&3)   (contiguous b128)
//     read  base = w*64 + g*16 + i16  -> 64 consecutive floats per wave
//     = 2 lanes/bank (conflict-free; round 12's 64g-strided read was 4-way,
//       SQ_LDS_BANK_CONFLICT 5.06e7).
//   REDUCE: lane (g=l&3, i16=l>>2) owns row ro = 64g + 16w + i16; sums 4
//     wave partials + bias, activates, quad-DPP i/f/g/o, redundant c/h per
//     quad, then 16 v_readlane -> SGPR h-broadcast for the next step.
extern "C" __global__ void __launch_bounds__(256, 1)
lstm_fused_kernel(const float* __restrict__ x,
                  const float* __restrict__ w_ih,
                  const float* __restrict__ w_hh,
                  const float* __restrict__ b_ih,
                  const float* __restrict__ b_hh,
                  const float* __restrict__ fc_w,
                  const float* __restrict__ fc_b,
                  float* __restrict__ out)
{
    __shared__ __align__(16) float xbuf[TCH * 16];        // 32 KiB (x quarter)
    __shared__ __align__(16) float pbuf[2][4][256];       // 8 KiB partials
    __shared__ __align__(16) float hist[CHUNK][Hn];       // 4 KiB (fc only)

    const int tid  = threadIdx.x;
    const int lane = tid & 63;
    const int w    = tid >> 6;          // wave id 0..3
    const int g    = lane & 3;          // gate type 0:i 1:f 2:g 3:o
    const int i16  = lane >> 2;         // 0..15
    const int jown = 16 * w + i16;      // h index owned in reduce phase
    const int ro   = 64 * g + jown;     // output row in reduce phase
    const int b    = blockIdx.x;

    const int wbase = ((lane >> 2) & 3) * 64 + (lane >> 4) * 16 + 4 * (lane & 3);
    const int rbase = w * 64 + g * 16 + i16;

    const float4* xsrc4 = (const float4*)(x + (size_t)b * Tn * In);

    // ---- zero the x padding columns (i = 12..15) once ----
    #pragma unroll
    for (int k = 0; k < 8; ++k) {
        int idx = tid + k * 256;                       // 0..2047
        xbuf[(idx >> 2) * 16 + 12 + (idx & 3)] = 0.0f;
    }

    // ---- per-lane weight slices (rows 4*lane..4*lane+3, K-slice of wave) ----
    float whh_s[4][16];
    #pragma unroll
    for (int r = 0; r < 4; ++r) {
        const float4* src = (const float4*)(w_hh + (4 * lane + r) * Hn + 16 * w);
        float4 v0 = src[0], v1 = src[1], v2 = src[2], v3 = src[3];
        whh_s[r][0]=v0.x;  whh_s[r][1]=v0.y;  whh_s[r][2]=v0.z;  whh_s[r][3]=v0.w;
        whh_s[r][4]=v1.x;  whh_s[r][5]=v1.y;  whh_s[r][6]=v1.z;  whh_s[r][7]=v1.w;
        whh_s[r][8]=v2.x;  whh_s[r][9]=v2.y;  whh_s[r][10]=v2.z; whh_s[r][11]=v2.w;
        whh_s[r][12]=v3.x; whh_s[r][13]=v3.y; whh_s[r][14]=v3.z; whh_s[r][15]=v3.w;
    }
    #pragma unroll
    for (int r = 0; r < 4; ++r)
        #pragma unroll
        for (int k = 0; k < 16; k += 4)
            asm volatile("" : "+v"(whh_s[r][k+0]), "+v"(whh_s[r][k+1]),
                              "+v"(whh_s[r][k+2]), "+v"(whh_s[r][k+3]));

    float wih_s[4][4];
    if (w < 3) {
        #pragma unroll
        for (int r = 0; r < 4; ++r) {
            float4 v = *(const float4*)(w_ih + (4 * lane + r) * In + 4 * w);
            wih_s[r][0]=v.x; wih_s[r][1]=v.y; wih_s[r][2]=v.z; wih_s[r][3]=v.w;
        }
    } else {
        #pragma unroll
        for (int r = 0; r < 4; ++r)
            wih_s[r][0]=wih_s[r][1]=wih_s[r][2]=wih_s[r][3]=0.0f;
    }
    #pragma unroll
    for (int r = 0; r < 4; ++r)
        asm volatile("" : "+v"(wih_s[r][0]), "+v"(wih_s[r][1]),
                          "+v"(wih_s[r][2]), "+v"(wih_s[r][3]));

    const float bias = b_ih[ro] + b_hh[ro];
    // act = m * sigma(m*a) - (m-1):  g!=2 -> sigma(a);  g==2 -> tanh(a)
    const float m    = (g == 2) ? 2.0f : 1.0f;
    const float madd = (g == 2) ? -1.0f : 0.0f;
    const float me   = (g == 2) ? (-2.0f * LOG2E) : (-LOG2E);
    // fc flush constants
    const int   fq   = tid & 15;
    const int   fs   = tid >> 4;
    const float4 fw4 = *(const float4*)(fc_w + 4 * fq);
    const float fcb  = fc_b[0];

    float h_own = 0.0f;                 // h[jown] (quad-redundant)
    float c     = 0.0f;                 // cell state for jown (quad-redundant)

    float* outb = out + (size_t)b * Tn;

    for (int ci = 0; ci < Tn / CHUNK; ++ci) {
        const int T0 = ci * CHUNK;

        // ---- stage x quarter (previous quarter fully consumed pre-barrier) ----
        if ((T0 & (TCH - 1)) == 0) {
            const int qtr = T0 >> 9;
            #pragma unroll
            for (int k = 0; k < 6; ++k) {
                int li  = tid + k * 256;              // 0..1535 (local float4)
                int t_l = li / 3;                     // local step
                int i4  = li % 3;                     // float4 slot within row
                ((float4*)xbuf)[t_l * 4 + i4] = xsrc4[qtr * 1536 + li];
            }
            __syncthreads();
        }

        #pragma unroll
        for (int s = 0; s < CHUNK; ++s) {
            const int tl = (T0 + s) & (TCH - 1);

            // ---- SGPR h-broadcast from previous step (quad lane 4k holds h[16w+k]) ----
            float hs0  = rdl(h_own,  0), hs1  = rdl(h_own,  4);
            float hs2  = rdl(h_own,  8), hs3  = rdl(h_own, 12);
            float hs4  = rdl(h_own, 16), hs5  = rdl(h_own, 20);
            float hs6  = rdl(h_own, 24), hs7  = rdl(h_own, 28);
            float hs8  = rdl(h_own, 32), hs9  = rdl(h_own, 36);
            float hs10 = rdl(h_own, 40), hs11 = rdl(h_own, 44);
            float hs12 = rdl(h_own, 48), hs13 = rdl(h_own, 52);
            float hs14 = rdl(h_own, 56), hs15 = rdl(h_own, 60);

            // ---- partial phase: rows 4*lane..4*lane+3 over wave's K-slice ----
            // h-FMAs first; x read + x-FMAs last (x ds_read latency hides).
            const float4 xv = *(const float4*)(xbuf + tl * 16 + 4 * w);
            float p0 = hs0 * whh_s[0][0], p1 = hs0 * whh_s[1][0];
            float p2 = hs0 * whh_s[2][0], p3 = hs0 * whh_s[3][0];
            #define HFMA(K, HS) \
                p0 = fmaf(HS, whh_s[0][K], p0);  p1 = fmaf(HS, whh_s[1][K], p1); \
                p2 = fmaf(HS, whh_s[2][K], p2);  p3 = fmaf(HS, whh_s[3][K], p3);
            HFMA(1,  hs1)  HFMA(2,  hs2)  HFMA(3,  hs3)
            HFMA(4,  hs4)  HFMA(5,  hs5)  HFMA(6,  hs6)  HFMA(7,  hs7)
            HFMA(8,  hs8)  HFMA(9,  hs9)  HFMA(10, hs10) HFMA(11, hs11)
            HFMA(12, hs12) HFMA(13, hs13) HFMA(14, hs14) HFMA(15, hs15)
            #undef HFMA
            p0 = fmaf(xv.x, wih_s[0][0], p0);  p1 = fmaf(xv.x, wih_s[1][0], p1);
            p2 = fmaf(xv.x, wih_s[2][0], p2);  p3 = fmaf(xv.x, wih_s[3][0], p3);
            p0 = fmaf(xv.y, wih_s[0][1], p0);  p1 = fmaf(xv.y, wih_s[1][1], p1);
            p2 = fmaf(xv.y, wih_s[2][1], p2);  p3 = fmaf(xv.y, wih_s[3][1], p3);
            p0 = fmaf(xv.z, wih_s[0][2], p0);  p1 = fmaf(xv.z, wih_s[1][2], p1);
            p2 = fmaf(xv.z, wih_s[2][2], p2);  p3 = fmaf(xv.z, wih_s[3][2], p3);
            p0 = fmaf(xv.w, wih_s[0][3], p0);  p1 = fmaf(xv.w, wih_s[1][3], p1);
            p2 = fmaf(xv.w, wih_s[2][3], p2);  p3 = fmaf(xv.w, wih_s[3][3], p3);

            float4 pv; pv.x = p0; pv.y = p1; pv.z = p2; pv.w = p3;
            *(float4*)(&pbuf[s & 1][w][wbase]) = pv;
            __syncthreads();               // the ONE barrier per step

            // ---- reduce phase: own row ro (conflict-free reads) ----
            const float* pb = &pbuf[s & 1][0][0];
            float a = ((pb[rbase] + pb[256 + rbase]) +
                       (pb[512 + rbase] + pb[768 + rbase])) + bias;
            float e   = exp2f(me * a);
            float act = fmaf(m, frcp(1.0f + e), madd);

            // quad broadcasts: every lane gets labeled i/f/g/o
            float iv = dppq<0x00>(act);
            float fv = dppq<0x55>(act);
            float gv = dppq<0xAA>(act);
            float ov = dppq<0xFF>(act);

            c = fmaf(fv, c, iv * gv);                  // redundant per quad
            float e2 = exp2f(-2.0f * LOG2E * c);
            h_own = ov * fmaf(2.0f, frcp(1.0f + e2), -1.0f);

            if (g == 0) hist[s][jown] = h_own;         // fc history only
        }

        // ---- fc flush (needs all waves' hist writes of this chunk) ----
        __syncthreads();
        {
            const float4 hv = *(const float4*)(&hist[fs][4 * fq]);
            float pp = hv.x * fw4.x + hv.y * fw4.y + hv.z * fw4.z + hv.w * fw4.w;
            #pragma unroll
            for (int off = 8; off; off >>= 1)
                pp += __shfl_xor(pp, off, 16);
            if (fq == 0) outb[T0 + fs] = pp + fcb;
        }
    }
}

extern "C" void kernel_launch(void* const* d_in, const int* in_sizes, int n_in,
                              void* d_out, int out_size, void* d_ws, size_t ws_size,
                              hipStream_t stream) {
    const float* x    = (const float*)d_in[0];
    const float* w_ih = (const float*)d_in[1];
    const float* w_hh = (const float*)d_in[2];
    const float* b_ih = (const float*)d_in[3];
    const float* b_hh = (const float*)d_in[4];
    const float* fc_w = (const float*)d_in[5];
    const float* fc_b = (const float*)d_in[6];
    float* out = (float*)d_out;

    lstm_fused_kernel<<<Bn, 256, 0, stream>>>(x, w_ih, w_hh, b_ih, b_hh,
                                              fc_w, fc_b, out);
}